// Round 1
// baseline (1318.907 us; speedup 1.0000x reference)
//
#include <hip/hip_runtime.h>
#include <cmath>

#define NT 256   // threads per block
#define NB 32    // nodes per block

// thread tiling: jq = tid&31 -> features [jq*4, jq*4+4); iq = tid>>5 -> nodes [iq*4, iq*4+4)

__device__ __forceinline__ float sigmoid_(float v) {
    return 1.0f / (1.0f + expf(-v));
}

// ---------------- leaf level: h = (1-sigmoid(wf)) * tanh(whc) ----------------
__global__ __launch_bounds__(NT) void tree_leaf(
    const float* __restrict__ x,
    const float* __restrict__ Ww,   // [256][128]
    const float* __restrict__ Wb,   // [256]
    float* __restrict__ h,          // [n][128]
    int start, int size)
{
    __shared__ float sA[NB * 128];      // x tile
    __shared__ float sW[16 * 260];      // weight tile, [k][j2] stride 260

    const int tid = threadIdx.x;
    const int nbase = blockIdx.x * NB;
    const int s0 = start + nbase;
    const int nb = min(NB, size - nbase);

    const int jq = tid & 31;
    const int iq = tid >> 5;
    const int j0 = jq << 2;
    const int i0 = iq << 2;

    // load x tile (coalesced float4)
    {
        const float4* xg = (const float4*)(x + (size_t)s0 * 128);
        float4* sA4 = (float4*)sA;
        for (int idx = tid; idx < nb * 32; idx += NT) sA4[idx] = xg[idx];
    }

    float whc[4][4], wf[4][4];
#pragma unroll
    for (int j = 0; j < 4; ++j)
#pragma unroll
        for (int i = 0; i < 4; ++i) { whc[j][i] = 0.f; wf[j][i] = 0.f; }

    for (int k0 = 0; k0 < 128; k0 += 16) {
        __syncthreads();
        // stage Ww[:, k0:k0+16] -> sW[k][j2]
        {
            const float4* Wg = (const float4*)Ww;
            for (int idx = tid; idx < 256 * 4; idx += NT) {
                int j2 = idx >> 2, kq = idx & 3;
                float4 v = Wg[j2 * 32 + (k0 >> 2) + kq];
                int kb = kq << 2;
                sW[(kb + 0) * 260 + j2] = v.x;
                sW[(kb + 1) * 260 + j2] = v.y;
                sW[(kb + 2) * 260 + j2] = v.z;
                sW[(kb + 3) * 260 + j2] = v.w;
            }
        }
        __syncthreads();
#pragma unroll
        for (int kk = 0; kk < 16; kk += 4) {
            float4 a4[4];
#pragma unroll
            for (int i = 0; i < 4; ++i)
                a4[i] = ((const float4*)sA)[(i0 + i) * 32 + ((k0 + kk) >> 2)];
#pragma unroll
            for (int u = 0; u < 4; ++u) {
                int k = kk + u;
                float4 w0 = *((const float4*)&sW[k * 260 + j0]);
                float4 w1 = *((const float4*)&sW[k * 260 + 128 + j0]);
                const float* w0p = (const float*)&w0;
                const float* w1p = (const float*)&w1;
#pragma unroll
                for (int i = 0; i < 4; ++i) {
                    float av = ((const float*)&a4[i])[u];
#pragma unroll
                    for (int j = 0; j < 4; ++j) {
                        whc[j][i] = fmaf(w0p[j], av, whc[j][i]);
                        wf[j][i]  = fmaf(w1p[j], av, wf[j][i]);
                    }
                }
            }
        }
    }

    // bias + activation + store
#pragma unroll
    for (int i = 0; i < 4; ++i) {
        if (i0 + i < nb) {
            float4 o;
            float* op = (float*)&o;
#pragma unroll
            for (int j = 0; j < 4; ++j) {
                float vhc = whc[j][i] + Wb[j0 + j];
                float vf  = wf[j][i]  + Wb[128 + j0 + j];
                float f = sigmoid_(vf);
                op[j] = (1.0f - f) * tanhf(vhc);
            }
            *(float4*)&h[((size_t)(s0 + i0 + i)) * 128 + j0] = o;
        }
    }
}

// ---------------- internal levels ----------------
__global__ __launch_bounds__(NT) void tree_internal(
    const float* __restrict__ x,
    const float* __restrict__ Ww,   // [256][128]
    const float* __restrict__ Wb,   // [256]
    const float* __restrict__ Uf,   // [128][256]
    const float* __restrict__ Uhc,  // [128][256]
    float* __restrict__ h,          // [n][128]
    int start, int size)
{
    __shared__ float sA[NB * 256];      // x tile (first NB*128) then hcat (NB*256)
    __shared__ float sW[4224];          // weight tile: P1 [16][260], P2/P3 [32][132]

    const int tid = threadIdx.x;
    const int nbase = blockIdx.x * NB;
    const int s0 = start + nbase;
    const int nb = min(NB, size - nbase);

    const int jq = tid & 31;
    const int iq = tid >> 5;
    const int j0 = jq << 2;
    const int i0 = iq << 2;

    // ---- load x tile ----
    {
        const float4* xg = (const float4*)(x + (size_t)s0 * 128);
        float4* sA4 = (float4*)sA;
        for (int idx = tid; idx < nb * 32; idx += NT) sA4[idx] = xg[idx];
    }

    // ---- P1: wx = x @ Ww^T (+bias later) ----
    float whc[4][4], wf[4][4];
#pragma unroll
    for (int j = 0; j < 4; ++j)
#pragma unroll
        for (int i = 0; i < 4; ++i) { whc[j][i] = 0.f; wf[j][i] = 0.f; }

    for (int k0 = 0; k0 < 128; k0 += 16) {
        __syncthreads();
        {
            const float4* Wg = (const float4*)Ww;
            for (int idx = tid; idx < 256 * 4; idx += NT) {
                int j2 = idx >> 2, kq = idx & 3;
                float4 v = Wg[j2 * 32 + (k0 >> 2) + kq];
                int kb = kq << 2;
                sW[(kb + 0) * 260 + j2] = v.x;
                sW[(kb + 1) * 260 + j2] = v.y;
                sW[(kb + 2) * 260 + j2] = v.z;
                sW[(kb + 3) * 260 + j2] = v.w;
            }
        }
        __syncthreads();
#pragma unroll
        for (int kk = 0; kk < 16; kk += 4) {
            float4 a4[4];
#pragma unroll
            for (int i = 0; i < 4; ++i)
                a4[i] = ((const float4*)sA)[(i0 + i) * 32 + ((k0 + kk) >> 2)];
#pragma unroll
            for (int u = 0; u < 4; ++u) {
                int k = kk + u;
                float4 w0 = *((const float4*)&sW[k * 260 + j0]);
                float4 w1 = *((const float4*)&sW[k * 260 + 128 + j0]);
                const float* w0p = (const float*)&w0;
                const float* w1p = (const float*)&w1;
#pragma unroll
                for (int i = 0; i < 4; ++i) {
                    float av = ((const float*)&a4[i])[u];
#pragma unroll
                    for (int j = 0; j < 4; ++j) {
                        whc[j][i] = fmaf(w0p[j], av, whc[j][i]);
                        wf[j][i]  = fmaf(w1p[j], av, wf[j][i]);
                    }
                }
            }
        }
    }
#pragma unroll
    for (int j = 0; j < 4; ++j) {
        float bhc = Wb[j0 + j];
        float bf  = Wb[128 + j0 + j];
#pragma unroll
        for (int i = 0; i < 4; ++i) { whc[j][i] += bhc; wf[j][i] += bf; }
    }

    // ---- load hcat (children h rows, contiguous) ----
    __syncthreads();   // all P1 reads of sA done
    {
        const float4* hg = (const float4*)(h + ((size_t)2 * s0 + 1) * 128);
        float4* sA4 = (float4*)sA;
        for (int idx = tid; idx < nb * 64; idx += NT) sA4[idx] = hg[idx];
    }

    // ---- P2: f = sigmoid(Uf @ hcat + wf) ----
    float fv[4][4];
#pragma unroll
    for (int j = 0; j < 4; ++j)
#pragma unroll
        for (int i = 0; i < 4; ++i) fv[j][i] = 0.f;

    for (int k0 = 0; k0 < 256; k0 += 32) {
        __syncthreads();
        {
            const float4* Ug = (const float4*)Uf;
            for (int idx = tid; idx < 128 * 8; idx += NT) {
                int j2 = idx >> 3, kq = idx & 7;
                float4 v = Ug[j2 * 64 + (k0 >> 2) + kq];
                int kb = kq << 2;
                sW[(kb + 0) * 132 + j2] = v.x;
                sW[(kb + 1) * 132 + j2] = v.y;
                sW[(kb + 2) * 132 + j2] = v.z;
                sW[(kb + 3) * 132 + j2] = v.w;
            }
        }
        __syncthreads();
#pragma unroll
        for (int kk = 0; kk < 32; kk += 4) {
            float4 a4[4];
#pragma unroll
            for (int i = 0; i < 4; ++i)
                a4[i] = ((const float4*)sA)[(i0 + i) * 64 + ((k0 + kk) >> 2)];
#pragma unroll
            for (int u = 0; u < 4; ++u) {
                int k = kk + u;
                float4 w = *((const float4*)&sW[k * 132 + j0]);
                const float* wp = (const float*)&w;
#pragma unroll
                for (int i = 0; i < 4; ++i) {
                    float av = ((const float*)&a4[i])[u];
#pragma unroll
                    for (int j = 0; j < 4; ++j)
                        fv[j][i] = fmaf(wp[j], av, fv[j][i]);
                }
            }
        }
    }
#pragma unroll
    for (int j = 0; j < 4; ++j)
#pragma unroll
        for (int i = 0; i < 4; ++i)
            fv[j][i] = sigmoid_(fv[j][i] + wf[j][i]);

    // ---- hsum (registers) + scale hcat in place by f_rep ----
    __syncthreads();   // all P2 reads of hcat done
    float hs[4][4];
#pragma unroll
    for (int i = 0; i < 4; ++i) {
        float4* row = (float4*)&sA[(i0 + i) * 256];
        float4 c0 = row[jq];
        float4 c1 = row[32 + jq];
        hs[0][i] = c0.x + c1.x;
        hs[1][i] = c0.y + c1.y;
        hs[2][i] = c0.z + c1.z;
        hs[3][i] = c0.w + c1.w;
        c0.x *= fv[0][i]; c0.y *= fv[1][i]; c0.z *= fv[2][i]; c0.w *= fv[3][i];
        c1.x *= fv[0][i]; c1.y *= fv[1][i]; c1.z *= fv[2][i]; c1.w *= fv[3][i];
        row[jq] = c0;
        row[32 + jq] = c1;
    }

    // ---- P3: cand = Uhc @ (f_rep*hcat) ----
    float cv[4][4];
#pragma unroll
    for (int j = 0; j < 4; ++j)
#pragma unroll
        for (int i = 0; i < 4; ++i) cv[j][i] = 0.f;

    for (int k0 = 0; k0 < 256; k0 += 32) {
        __syncthreads();   // fences scale-writes (first iter) and sW reuse
        {
            const float4* Ug = (const float4*)Uhc;
            for (int idx = tid; idx < 128 * 8; idx += NT) {
                int j2 = idx >> 3, kq = idx & 7;
                float4 v = Ug[j2 * 64 + (k0 >> 2) + kq];
                int kb = kq << 2;
                sW[(kb + 0) * 132 + j2] = v.x;
                sW[(kb + 1) * 132 + j2] = v.y;
                sW[(kb + 2) * 132 + j2] = v.z;
                sW[(kb + 3) * 132 + j2] = v.w;
            }
        }
        __syncthreads();
#pragma unroll
        for (int kk = 0; kk < 32; kk += 4) {
            float4 a4[4];
#pragma unroll
            for (int i = 0; i < 4; ++i)
                a4[i] = ((const float4*)sA)[(i0 + i) * 64 + ((k0 + kk) >> 2)];
#pragma unroll
            for (int u = 0; u < 4; ++u) {
                int k = kk + u;
                float4 w = *((const float4*)&sW[k * 132 + j0]);
                const float* wp = (const float*)&w;
#pragma unroll
                for (int i = 0; i < 4; ++i) {
                    float av = ((const float*)&a4[i])[u];
#pragma unroll
                    for (int j = 0; j < 4; ++j)
                        cv[j][i] = fmaf(wp[j], av, cv[j][i]);
                }
            }
        }
    }

    // ---- epilogue: h = f*hsum + (1-f)*tanh(cand + whc) ----
#pragma unroll
    for (int i = 0; i < 4; ++i) {
        if (i0 + i < nb) {
            float4 o;
            float* op = (float*)&o;
#pragma unroll
            for (int j = 0; j < 4; ++j) {
                float t = tanhf(cv[j][i] + whc[j][i]);
                op[j] = fv[j][i] * hs[j][i] + (1.0f - fv[j][i]) * t;
            }
            *(float4*)&h[((size_t)(s0 + i0 + i)) * 128 + j0] = o;
        }
    }
}

extern "C" void kernel_launch(void* const* d_in, const int* in_sizes, int n_in,
                              void* d_out, int out_size, void* d_ws, size_t ws_size,
                              hipStream_t stream)
{
    (void)in_sizes; (void)n_in; (void)d_ws; (void)ws_size; (void)out_size;
    const float* x   = (const float*)d_in[0];
    const float* Ww  = (const float*)d_in[1];
    const float* Wb  = (const float*)d_in[2];
    const float* Uf  = (const float*)d_in[3];
    const float* Uhc = (const float*)d_in[4];
    float* h = (float*)d_out;

    const int depth = 18;

    // leaves (level depth-1), bottom-up
    {
        int lvl = depth - 1;
        int start = (1 << lvl) - 1;
        int size  = 1 << lvl;
        int grid = (size + NB - 1) / NB;
        tree_leaf<<<grid, NT, 0, stream>>>(x, Ww, Wb, h, start, size);
    }
    for (int lvl = depth - 2; lvl >= 0; --lvl) {
        int start = (1 << lvl) - 1;
        int size  = 1 << lvl;
        int grid = (size + NB - 1) / NB;
        tree_internal<<<grid, NT, 0, stream>>>(x, Ww, Wb, Uf, Uhc, h, start, size);
    }
}

// Round 2
// 966.443 us; speedup vs baseline: 1.3647x; 1.3647x over previous
//
#include <hip/hip_runtime.h>
#include <cmath>

#define NT 256

// ---- problem constants (DEPTH=18, N_ARY=2, H=128, X=128) ----
#define NTOT   262143     // 2^18 - 1
#define NINT   131071     // internal nodes: ids 0 .. 131070
#define LEAF0  131071     // first leaf id
#define NLEAF  131072

// ws layout (floats)
#define WHC_OFF  0                         // [NINT][128]
#define WF_OFF   (NINT * 128)              // [NINT][128]
#define WWT_OFF  (2 * NINT * 128)          // [128][256]  WwT[k][j] = Ww[j][k]
#define UFT_OFF  (WWT_OFF + 128 * 256)     // [256][128]  UfT[k][j] = Uf[j][k]
#define UHCT_OFF (UFT_OFF + 256 * 128)     // [256][128]
#define WS_FLOATS (UHCT_OFF + 256 * 128)
#define WS_BYTES  ((size_t)WS_FLOATS * 4)  // ~134.6 MB

__device__ __forceinline__ float sigmoid_(float v) {
    return 1.0f / (1.0f + expf(-v));
}

// =================== new path ===================

__global__ __launch_bounds__(NT) void transpose_weights(
    const float* __restrict__ Ww, const float* __restrict__ Uf,
    const float* __restrict__ Uhc, float* __restrict__ ws)
{
    int t = blockIdx.x * NT + threadIdx.x;
    if (t < 128 * 256) {                 // WwT
        int k = t >> 8, j = t & 255;
        ws[WWT_OFF + t] = Ww[j * 128 + k];
    } else if (t < 2 * 32768) {          // UfT
        int u = t - 32768;
        int k = u >> 7, j = u & 127;
        ws[UFT_OFF + u] = Uf[j * 256 + k];
    } else if (t < 3 * 32768) {          // UhcT
        int u = t - 2 * 32768;
        int k = u >> 7, j = u & 127;
        ws[UHCT_OFF + u] = Uhc[j * 256 + k];
    }
}

// wx for all internal nodes: whc_ws / wf_ws = x @ Ww^T + Wb
// block: 16 nodes; thread tile: 4 features (of 256) x 4 nodes
#define A_NB 16
__global__ __launch_bounds__(NT) void wx_internal(
    const float* __restrict__ x, const float* __restrict__ ws_all,
    const float* __restrict__ Wb, float* __restrict__ ws)
{
    __shared__ float sX[A_NB * 128];    // 8 KB
    const float* wwt = ws_all + WWT_OFF;
    const int tid = threadIdx.x;
    const int nbase = blockIdx.x * A_NB;
    const int nb = min(A_NB, NINT - nbase);

    const int jq = tid & 63;  const int j0 = jq << 2;   // 0..255
    const int iq = tid >> 6;  const int i0 = iq << 2;   // 0..15

    {
        const float4* xg = (const float4*)(x + (size_t)nbase * 128);
        float4* sX4 = (float4*)sX;
        for (int idx = tid; idx < nb * 32; idx += NT) sX4[idx] = xg[idx];
    }
    __syncthreads();

    float acc[4][4];
#pragma unroll
    for (int j = 0; j < 4; ++j)
#pragma unroll
        for (int i = 0; i < 4; ++i) acc[j][i] = 0.f;

    const float4* sX4 = (const float4*)sX;
    for (int k0 = 0; k0 < 128; k0 += 8) {
        float4 w[8];
#pragma unroll
        for (int u = 0; u < 8; ++u)
            w[u] = *(const float4*)&wwt[(k0 + u) * 256 + j0];
        float4 a[4][2];
#pragma unroll
        for (int i = 0; i < 4; ++i) {
            a[i][0] = sX4[(i0 + i) * 32 + (k0 >> 2)];
            a[i][1] = sX4[(i0 + i) * 32 + (k0 >> 2) + 1];
        }
#pragma unroll
        for (int u = 0; u < 8; ++u) {
            const float* wp = (const float*)&w[u];
#pragma unroll
            for (int i = 0; i < 4; ++i) {
                float av = ((const float*)&a[i][u >> 2])[u & 3];
#pragma unroll
                for (int j = 0; j < 4; ++j)
                    acc[j][i] = fmaf(wp[j], av, acc[j][i]);
            }
        }
    }

    float* dst = (j0 < 128) ? (ws + WHC_OFF) : (ws + WF_OFF);
    const int jo = j0 & 127;
#pragma unroll
    for (int i = 0; i < 4; ++i) {
        if (i0 + i < nb) {
            float4 o;
            float* op = (float*)&o;
#pragma unroll
            for (int j = 0; j < 4; ++j) op[j] = acc[j][i] + Wb[j0 + j];
            *(float4*)&dst[(size_t)(nbase + i0 + i) * 128 + jo] = o;
        }
    }
}

// leaves: h = (1 - sigmoid(wf)) * tanh(whc), computed directly from x
// block: 32 nodes; thread tile: 4 features (of 128) x 4 nodes, two accum sets
#define L_NB 32
__global__ __launch_bounds__(NT) void leaf_kernel(
    const float* __restrict__ x, const float* __restrict__ ws_all,
    const float* __restrict__ Wb, float* __restrict__ h)
{
    __shared__ float sX[L_NB * 128];    // 16 KB
    const float* wwt = ws_all + WWT_OFF;
    const int tid = threadIdx.x;
    const int nbase = blockIdx.x * L_NB;            // leaf-local, exact multiple
    const int g0 = LEAF0 + nbase;

    const int jq = tid & 31;  const int j0 = jq << 2;   // 0..127
    const int iq = tid >> 5;  const int i0 = iq << 2;   // 0..31

    {
        const float4* xg = (const float4*)(x + (size_t)g0 * 128);
        float4* sX4 = (float4*)sX;
        for (int idx = tid; idx < L_NB * 32; idx += NT) sX4[idx] = xg[idx];
    }
    __syncthreads();

    float ahc[4][4], af[4][4];
#pragma unroll
    for (int j = 0; j < 4; ++j)
#pragma unroll
        for (int i = 0; i < 4; ++i) { ahc[j][i] = 0.f; af[j][i] = 0.f; }

    const float4* sX4 = (const float4*)sX;
    for (int k0 = 0; k0 < 128; k0 += 8) {
        float4 w0[8], w1[8];
#pragma unroll
        for (int u = 0; u < 8; ++u) {
            w0[u] = *(const float4*)&wwt[(k0 + u) * 256 + j0];
            w1[u] = *(const float4*)&wwt[(k0 + u) * 256 + 128 + j0];
        }
        float4 a[4][2];
#pragma unroll
        for (int i = 0; i < 4; ++i) {
            a[i][0] = sX4[(i0 + i) * 32 + (k0 >> 2)];
            a[i][1] = sX4[(i0 + i) * 32 + (k0 >> 2) + 1];
        }
#pragma unroll
        for (int u = 0; u < 8; ++u) {
            const float* w0p = (const float*)&w0[u];
            const float* w1p = (const float*)&w1[u];
#pragma unroll
            for (int i = 0; i < 4; ++i) {
                float av = ((const float*)&a[i][u >> 2])[u & 3];
#pragma unroll
                for (int j = 0; j < 4; ++j) {
                    ahc[j][i] = fmaf(w0p[j], av, ahc[j][i]);
                    af[j][i]  = fmaf(w1p[j], av, af[j][i]);
                }
            }
        }
    }

#pragma unroll
    for (int i = 0; i < 4; ++i) {
        float4 o;
        float* op = (float*)&o;
#pragma unroll
        for (int j = 0; j < 4; ++j) {
            float f = sigmoid_(af[j][i] + Wb[128 + j0 + j]);
            op[j] = (1.0f - f) * tanhf(ahc[j][i] + Wb[j0 + j]);
        }
        *(float4*)&h[(size_t)(g0 + i0 + i) * 128 + j0] = o;
    }
}

// internal level: P2/P3 GEMVs with weights streamed from L2, hcat in LDS
// block: 32 nodes; thread tile: 4 features x 4 nodes
#define B_NB 32
__global__ __launch_bounds__(NT) void level_kernel(
    const float* __restrict__ ws_all, float* __restrict__ h,
    int start, int size)
{
    __shared__ float sH[B_NB * 256];    // 32 KB
    const float* uft  = ws_all + UFT_OFF;
    const float* uhct = ws_all + UHCT_OFF;
    const float* whcw = ws_all + WHC_OFF;
    const float* wfw  = ws_all + WF_OFF;

    const int tid = threadIdx.x;
    const int nbase = blockIdx.x * B_NB;
    const int s0 = start + nbase;
    const int nb = min(B_NB, size - nbase);

    const int jq = tid & 31;  const int j0 = jq << 2;
    const int iq = tid >> 5;  const int i0 = iq << 2;

    // hcat = children h rows, contiguous
    {
        const float4* hg = (const float4*)(h + ((size_t)2 * s0 + 1) * 128);
        float4* sH4 = (float4*)sH;
        for (int idx = tid; idx < nb * 64; idx += NT) sH4[idx] = hg[idx];
    }
    __syncthreads();

    const float4* sH4 = (const float4*)sH;

    // ---- P2: f = sigmoid(Uf @ hcat + wf) ----
    float fv[4][4];
#pragma unroll
    for (int j = 0; j < 4; ++j)
#pragma unroll
        for (int i = 0; i < 4; ++i) fv[j][i] = 0.f;

    for (int k0 = 0; k0 < 256; k0 += 8) {
        float4 w[8];
#pragma unroll
        for (int u = 0; u < 8; ++u)
            w[u] = *(const float4*)&uft[(k0 + u) * 128 + j0];
        float4 a[4][2];
#pragma unroll
        for (int i = 0; i < 4; ++i) {
            a[i][0] = sH4[(i0 + i) * 64 + (k0 >> 2)];
            a[i][1] = sH4[(i0 + i) * 64 + (k0 >> 2) + 1];
        }
#pragma unroll
        for (int u = 0; u < 8; ++u) {
            const float* wp = (const float*)&w[u];
#pragma unroll
            for (int i = 0; i < 4; ++i) {
                float av = ((const float*)&a[i][u >> 2])[u & 3];
#pragma unroll
                for (int j = 0; j < 4; ++j)
                    fv[j][i] = fmaf(wp[j], av, fv[j][i]);
            }
        }
    }
#pragma unroll
    for (int i = 0; i < 4; ++i) {
        // reads stay in-bounds even for tail blocks (node <= start+31 < NINT)
        float4 wfv = *(const float4*)&wfw[(size_t)(s0 + i0 + i) * 128 + j0];
        const float* wfp = (const float*)&wfv;
#pragma unroll
        for (int j = 0; j < 4; ++j)
            fv[j][i] = sigmoid_(fv[j][i] + wfp[j]);
    }

    __syncthreads();   // all P2 reads of sH done

    // ---- hsum (regs) + scale hcat in place by f_rep ----
    float hs[4][4];
#pragma unroll
    for (int i = 0; i < 4; ++i) {
        float4* row = (float4*)&sH[(i0 + i) * 256];
        float4 c0 = row[jq];
        float4 c1 = row[32 + jq];
        hs[0][i] = c0.x + c1.x;
        hs[1][i] = c0.y + c1.y;
        hs[2][i] = c0.z + c1.z;
        hs[3][i] = c0.w + c1.w;
        c0.x *= fv[0][i]; c0.y *= fv[1][i]; c0.z *= fv[2][i]; c0.w *= fv[3][i];
        c1.x *= fv[0][i]; c1.y *= fv[1][i]; c1.z *= fv[2][i]; c1.w *= fv[3][i];
        row[jq] = c0;
        row[32 + jq] = c1;
    }
    __syncthreads();

    // ---- P3: cand = Uhc @ (f_rep * hcat) ----
    float cv[4][4];
#pragma unroll
    for (int j = 0; j < 4; ++j)
#pragma unroll
        for (int i = 0; i < 4; ++i) cv[j][i] = 0.f;

    for (int k0 = 0; k0 < 256; k0 += 8) {
        float4 w[8];
#pragma unroll
        for (int u = 0; u < 8; ++u)
            w[u] = *(const float4*)&uhct[(k0 + u) * 128 + j0];
        float4 a[4][2];
#pragma unroll
        for (int i = 0; i < 4; ++i) {
            a[i][0] = sH4[(i0 + i) * 64 + (k0 >> 2)];
            a[i][1] = sH4[(i0 + i) * 64 + (k0 >> 2) + 1];
        }
#pragma unroll
        for (int u = 0; u < 8; ++u) {
            const float* wp = (const float*)&w[u];
#pragma unroll
            for (int i = 0; i < 4; ++i) {
                float av = ((const float*)&a[i][u >> 2])[u & 3];
#pragma unroll
                for (int j = 0; j < 4; ++j)
                    cv[j][i] = fmaf(wp[j], av, cv[j][i]);
            }
        }
    }

    // ---- epilogue: h = f*hsum + (1-f)*tanh(cand + whc) ----
#pragma unroll
    for (int i = 0; i < 4; ++i) {
        if (i0 + i < nb) {
            float4 whcv = *(const float4*)&whcw[(size_t)(s0 + i0 + i) * 128 + j0];
            const float* wp = (const float*)&whcv;
            float4 o;
            float* op = (float*)&o;
#pragma unroll
            for (int j = 0; j < 4; ++j) {
                float t = tanhf(cv[j][i] + wp[j]);
                op[j] = fv[j][i] * hs[j][i] + (1.0f - fv[j][i]) * t;
            }
            *(float4*)&h[(size_t)(s0 + i0 + i) * 128 + j0] = o;
        }
    }
}

// =================== fallback path (round-1, no workspace) ===================

__global__ __launch_bounds__(NT) void fb_leaf(
    const float* __restrict__ x, const float* __restrict__ Ww,
    const float* __restrict__ Wb, float* __restrict__ h, int start, int size)
{
    __shared__ float sA[32 * 128];
    __shared__ float sW[16 * 260];
    const int tid = threadIdx.x;
    const int nbase = blockIdx.x * 32;
    const int s0 = start + nbase;
    const int nb = min(32, size - nbase);
    const int jq = tid & 31, iq = tid >> 5;
    const int j0 = jq << 2, i0 = iq << 2;
    {
        const float4* xg = (const float4*)(x + (size_t)s0 * 128);
        float4* sA4 = (float4*)sA;
        for (int idx = tid; idx < nb * 32; idx += NT) sA4[idx] = xg[idx];
    }
    float whc[4][4], wf[4][4];
#pragma unroll
    for (int j = 0; j < 4; ++j)
#pragma unroll
        for (int i = 0; i < 4; ++i) { whc[j][i] = 0.f; wf[j][i] = 0.f; }
    for (int k0 = 0; k0 < 128; k0 += 16) {
        __syncthreads();
        const float4* Wg = (const float4*)Ww;
        for (int idx = tid; idx < 256 * 4; idx += NT) {
            int j2 = idx >> 2, kq = idx & 3;
            float4 v = Wg[j2 * 32 + (k0 >> 2) + kq];
            int kb = kq << 2;
            sW[(kb + 0) * 260 + j2] = v.x; sW[(kb + 1) * 260 + j2] = v.y;
            sW[(kb + 2) * 260 + j2] = v.z; sW[(kb + 3) * 260 + j2] = v.w;
        }
        __syncthreads();
#pragma unroll
        for (int kk = 0; kk < 16; kk += 4) {
            float4 a4[4];
#pragma unroll
            for (int i = 0; i < 4; ++i)
                a4[i] = ((const float4*)sA)[(i0 + i) * 32 + ((k0 + kk) >> 2)];
#pragma unroll
            for (int u = 0; u < 4; ++u) {
                int k = kk + u;
                float4 w0 = *((const float4*)&sW[k * 260 + j0]);
                float4 w1 = *((const float4*)&sW[k * 260 + 128 + j0]);
                const float* w0p = (const float*)&w0;
                const float* w1p = (const float*)&w1;
#pragma unroll
                for (int i = 0; i < 4; ++i) {
                    float av = ((const float*)&a4[i])[u];
#pragma unroll
                    for (int j = 0; j < 4; ++j) {
                        whc[j][i] = fmaf(w0p[j], av, whc[j][i]);
                        wf[j][i]  = fmaf(w1p[j], av, wf[j][i]);
                    }
                }
            }
        }
    }
#pragma unroll
    for (int i = 0; i < 4; ++i) {
        if (i0 + i < nb) {
            float4 o; float* op = (float*)&o;
#pragma unroll
            for (int j = 0; j < 4; ++j) {
                float f = sigmoid_(wf[j][i] + Wb[128 + j0 + j]);
                op[j] = (1.0f - f) * tanhf(whc[j][i] + Wb[j0 + j]);
            }
            *(float4*)&h[((size_t)(s0 + i0 + i)) * 128 + j0] = o;
        }
    }
}

__global__ __launch_bounds__(NT) void fb_internal(
    const float* __restrict__ x, const float* __restrict__ Ww,
    const float* __restrict__ Wb, const float* __restrict__ Uf,
    const float* __restrict__ Uhc, float* __restrict__ h, int start, int size)
{
    __shared__ float sA[32 * 256];
    __shared__ float sW[4224];
    const int tid = threadIdx.x;
    const int nbase = blockIdx.x * 32;
    const int s0 = start + nbase;
    const int nb = min(32, size - nbase);
    const int jq = tid & 31, iq = tid >> 5;
    const int j0 = jq << 2, i0 = iq << 2;
    {
        const float4* xg = (const float4*)(x + (size_t)s0 * 128);
        float4* sA4 = (float4*)sA;
        for (int idx = tid; idx < nb * 32; idx += NT) sA4[idx] = xg[idx];
    }
    float whc[4][4], wf[4][4];
#pragma unroll
    for (int j = 0; j < 4; ++j)
#pragma unroll
        for (int i = 0; i < 4; ++i) { whc[j][i] = 0.f; wf[j][i] = 0.f; }
    for (int k0 = 0; k0 < 128; k0 += 16) {
        __syncthreads();
        const float4* Wg = (const float4*)Ww;
        for (int idx = tid; idx < 256 * 4; idx += NT) {
            int j2 = idx >> 2, kq = idx & 3;
            float4 v = Wg[j2 * 32 + (k0 >> 2) + kq];
            int kb = kq << 2;
            sW[(kb + 0) * 260 + j2] = v.x; sW[(kb + 1) * 260 + j2] = v.y;
            sW[(kb + 2) * 260 + j2] = v.z; sW[(kb + 3) * 260 + j2] = v.w;
        }
        __syncthreads();
#pragma unroll
        for (int kk = 0; kk < 16; kk += 4) {
            float4 a4[4];
#pragma unroll
            for (int i = 0; i < 4; ++i)
                a4[i] = ((const float4*)sA)[(i0 + i) * 32 + ((k0 + kk) >> 2)];
#pragma unroll
            for (int u = 0; u < 4; ++u) {
                int k = kk + u;
                float4 w0 = *((const float4*)&sW[k * 260 + j0]);
                float4 w1 = *((const float4*)&sW[k * 260 + 128 + j0]);
                const float* w0p = (const float*)&w0;
                const float* w1p = (const float*)&w1;
#pragma unroll
                for (int i = 0; i < 4; ++i) {
                    float av = ((const float*)&a4[i])[u];
#pragma unroll
                    for (int j = 0; j < 4; ++j) {
                        whc[j][i] = fmaf(w0p[j], av, whc[j][i]);
                        wf[j][i]  = fmaf(w1p[j], av, wf[j][i]);
                    }
                }
            }
        }
    }
#pragma unroll
    for (int j = 0; j < 4; ++j) {
        float bhc = Wb[j0 + j], bf = Wb[128 + j0 + j];
#pragma unroll
        for (int i = 0; i < 4; ++i) { whc[j][i] += bhc; wf[j][i] += bf; }
    }
    __syncthreads();
    {
        const float4* hg = (const float4*)(h + ((size_t)2 * s0 + 1) * 128);
        float4* sA4 = (float4*)sA;
        for (int idx = tid; idx < nb * 64; idx += NT) sA4[idx] = hg[idx];
    }
    float fv[4][4];
#pragma unroll
    for (int j = 0; j < 4; ++j)
#pragma unroll
        for (int i = 0; i < 4; ++i) fv[j][i] = 0.f;
    for (int k0 = 0; k0 < 256; k0 += 32) {
        __syncthreads();
        const float4* Ug = (const float4*)Uf;
        for (int idx = tid; idx < 128 * 8; idx += NT) {
            int j2 = idx >> 3, kq = idx & 7;
            float4 v = Ug[j2 * 64 + (k0 >> 2) + kq];
            int kb = kq << 2;
            sW[(kb + 0) * 132 + j2] = v.x; sW[(kb + 1) * 132 + j2] = v.y;
            sW[(kb + 2) * 132 + j2] = v.z; sW[(kb + 3) * 132 + j2] = v.w;
        }
        __syncthreads();
#pragma unroll
        for (int kk = 0; kk < 32; kk += 4) {
            float4 a4[4];
#pragma unroll
            for (int i = 0; i < 4; ++i)
                a4[i] = ((const float4*)sA)[(i0 + i) * 64 + ((k0 + kk) >> 2)];
#pragma unroll
            for (int u = 0; u < 4; ++u) {
                int k = kk + u;
                float4 w = *((const float4*)&sW[k * 132 + j0]);
                const float* wp = (const float*)&w;
#pragma unroll
                for (int i = 0; i < 4; ++i) {
                    float av = ((const float*)&a4[i])[u];
#pragma unroll
                    for (int j = 0; j < 4; ++j)
                        fv[j][i] = fmaf(wp[j], av, fv[j][i]);
                }
            }
        }
    }
#pragma unroll
    for (int j = 0; j < 4; ++j)
#pragma unroll
        for (int i = 0; i < 4; ++i)
            fv[j][i] = sigmoid_(fv[j][i] + wf[j][i]);
    __syncthreads();
    float hs[4][4];
#pragma unroll
    for (int i = 0; i < 4; ++i) {
        float4* row = (float4*)&sA[(i0 + i) * 256];
        float4 c0 = row[jq], c1 = row[32 + jq];
        hs[0][i] = c0.x + c1.x; hs[1][i] = c0.y + c1.y;
        hs[2][i] = c0.z + c1.z; hs[3][i] = c0.w + c1.w;
        c0.x *= fv[0][i]; c0.y *= fv[1][i]; c0.z *= fv[2][i]; c0.w *= fv[3][i];
        c1.x *= fv[0][i]; c1.y *= fv[1][i]; c1.z *= fv[2][i]; c1.w *= fv[3][i];
        row[jq] = c0; row[32 + jq] = c1;
    }
    float cv[4][4];
#pragma unroll
    for (int j = 0; j < 4; ++j)
#pragma unroll
        for (int i = 0; i < 4; ++i) cv[j][i] = 0.f;
    for (int k0 = 0; k0 < 256; k0 += 32) {
        __syncthreads();
        const float4* Ug = (const float4*)Uhc;
        for (int idx = tid; idx < 128 * 8; idx += NT) {
            int j2 = idx >> 3, kq = idx & 7;
            float4 v = Ug[j2 * 64 + (k0 >> 2) + kq];
            int kb = kq << 2;
            sW[(kb + 0) * 132 + j2] = v.x; sW[(kb + 1) * 132 + j2] = v.y;
            sW[(kb + 2) * 132 + j2] = v.z; sW[(kb + 3) * 132 + j2] = v.w;
        }
        __syncthreads();
#pragma unroll
        for (int kk = 0; kk < 32; kk += 4) {
            float4 a4[4];
#pragma unroll
            for (int i = 0; i < 4; ++i)
                a4[i] = ((const float4*)sA)[(i0 + i) * 64 + ((k0 + kk) >> 2)];
#pragma unroll
            for (int u = 0; u < 4; ++u) {
                int k = kk + u;
                float4 w = *((const float4*)&sW[k * 132 + j0]);
                const float* wp = (const float*)&w;
#pragma unroll
                for (int i = 0; i < 4; ++i) {
                    float av = ((const float*)&a4[i])[u];
#pragma unroll
                    for (int j = 0; j < 4; ++j)
                        cv[j][i] = fmaf(wp[j], av, cv[j][i]);
                }
            }
        }
    }
#pragma unroll
    for (int i = 0; i < 4; ++i) {
        if (i0 + i < nb) {
            float4 o; float* op = (float*)&o;
#pragma unroll
            for (int j = 0; j < 4; ++j) {
                float t = tanhf(cv[j][i] + whc[j][i]);
                op[j] = fv[j][i] * hs[j][i] + (1.0f - fv[j][i]) * t;
            }
            *(float4*)&h[((size_t)(s0 + i0 + i)) * 128 + j0] = o;
        }
    }
}

// =================== launcher ===================

extern "C" void kernel_launch(void* const* d_in, const int* in_sizes, int n_in,
                              void* d_out, int out_size, void* d_ws, size_t ws_size,
                              hipStream_t stream)
{
    (void)in_sizes; (void)n_in; (void)out_size;
    const float* x   = (const float*)d_in[0];
    const float* Ww  = (const float*)d_in[1];
    const float* Wb  = (const float*)d_in[2];
    const float* Uf  = (const float*)d_in[3];
    const float* Uhc = (const float*)d_in[4];
    float* h = (float*)d_out;
    const int depth = 18;

    if (ws_size >= WS_BYTES) {
        float* ws = (float*)d_ws;
        transpose_weights<<<(3 * 32768 + NT - 1) / NT, NT, 0, stream>>>(Ww, Uf, Uhc, ws);
        wx_internal<<<(NINT + A_NB - 1) / A_NB, NT, 0, stream>>>(x, ws, Wb, ws);
        leaf_kernel<<<NLEAF / L_NB, NT, 0, stream>>>(x, ws, Wb, h);
        for (int lvl = depth - 2; lvl >= 0; --lvl) {
            int start = (1 << lvl) - 1;
            int size  = 1 << lvl;
            int grid  = (size + B_NB - 1) / B_NB;
            level_kernel<<<grid, NT, 0, stream>>>(ws, h, start, size);
        }
    } else {
        // fallback: fused per-level path (no workspace)
        {
            int lvl = depth - 1;
            int start = (1 << lvl) - 1, size = 1 << lvl;
            fb_leaf<<<(size + 31) / 32, NT, 0, stream>>>(x, Ww, Wb, h, start, size);
        }
        for (int lvl = depth - 2; lvl >= 0; --lvl) {
            int start = (1 << lvl) - 1, size = 1 << lvl;
            fb_internal<<<(size + 31) / 32, NT, 0, stream>>>(x, Ww, Wb, Uf, Uhc, h, start, size);
        }
    }
}